// Round 7
// baseline (540.037 us; speedup 1.0000x reference)
//
#include <hip/hip_runtime.h>

// Problem constants
#define NV 65536     // flattened vectors (64*32*32)
#define KN 1024      // codebook size
#define DD 256       // embedding dim
#define DECAY_F 0.99f
#define OMD_F (1.0f - 0.99f)
#define EPS_F 1e-5f

typedef __attribute__((ext_vector_type(8))) short short8;
typedef __attribute__((ext_vector_type(16))) float f32x16;

// ---------------------------------------------------------------------------
// bf16 split helpers (RTNE)
// ---------------------------------------------------------------------------
__device__ __forceinline__ void bf16_split(float v, short& hi, short& lo) {
  unsigned u = __float_as_uint(v);
  unsigned hr = (u + 0x7FFFu + ((u >> 16) & 1u)) >> 16;
  float hf = __uint_as_float(hr << 16);
  float rem = v - hf;
  unsigned u2 = __float_as_uint(rem);
  unsigned lr = (u2 + 0x7FFFu + ((u2 >> 16) & 1u)) >> 16;
  hi = (short)hr;
  lo = (short)lr;
}

// ---------------------------------------------------------------------------
// Kernel 0a: split x into x_hi/x_lo bf16 arrays (same [N][D] layout).
// ---------------------------------------------------------------------------
__global__ __launch_bounds__(256) void split_x(const float* __restrict__ x,
                                               short* __restrict__ xhi,
                                               short* __restrict__ xlo) {
  const int i = (blockIdx.x * 256 + threadIdx.x) * 8;
  float v[8];
  *(float4*)(v + 0) = *(const float4*)(x + i);
  *(float4*)(v + 4) = *(const float4*)(x + i + 4);
  short8 h, l;
  #pragma unroll
  for (int j = 0; j < 8; j++) {
    short hh, ll;
    bf16_split(v[j], hh, ll);
    h[j] = hh; l[j] = ll;
  }
  *(short8*)(xhi + i) = h;
  *(short8*)(xlo + i) = l;
}

// ---------------------------------------------------------------------------
// Kernel 0b: split e into the MFMA-staging tiled layout.
// 32 tiles (cc 0..3, dc 0..7), each 16384 shorts:
//   [h(2)][db(4)][code(256)][8]   global code = cc*256+code, d = dc*32+db*8+j
// ---------------------------------------------------------------------------
__global__ __launch_bounds__(256) void prep_e(const float* __restrict__ emb,
                                              short* __restrict__ eT) {
  const int b = blockIdx.x;   // 0..31 = cc*8 + dc
  const int cc = b >> 3, dc = b & 7;
  const int c = threadIdx.x;  // code within chunk, 0..255
  const float* src = emb + (cc * 256 + c) * 256 + dc * 32;
  short* tile = eT + b * 16384;
  #pragma unroll
  for (int db = 0; db < 4; db++) {
    float v[8];
    *(float4*)(v + 0) = *(const float4*)(src + db * 8);
    *(float4*)(v + 4) = *(const float4*)(src + db * 8 + 4);
    short8 h, l;
    #pragma unroll
    for (int j = 0; j < 8; j++) {
      short hh, ll;
      bf16_split(v[j], hh, ll);
      h[j] = hh; l[j] = ll;
    }
    *(short8*)(tile + ((0 * 4 + db) * 256 + c) * 8) = h;
    *(short8*)(tile + ((1 * 4 + db) * 256 + c) * 8) = l;
  }
}

// ---------------------------------------------------------------------------
// Kernel 1: eSq[k] = ||embedding[k]||^2 (fp32). One wave per row.
// ---------------------------------------------------------------------------
__global__ __launch_bounds__(256) void esq_kernel(const float* __restrict__ emb,
                                                  float* __restrict__ eSq) {
  const int lane = threadIdx.x & 63;
  const int row = blockIdx.x * 4 + (threadIdx.x >> 6);
  const float4 v = *(const float4*)(emb + row * DD + lane * 4);
  float s = v.x * v.x + v.y * v.y + v.z * v.z + v.w * v.w;
  #pragma unroll
  for (int off = 32; off > 0; off >>= 1) s += __shfl_down(s, off, 64);
  if (lane == 0) eSq[row] = s;
}

// ---------------------------------------------------------------------------
// Kernel 2: MFMA distance + exact best-2 candidates.
// Block = 4 waves = 128 queries; wave = 32 q (1 A tile) x 256 codes (8 B
// tiles, acc[8] = 128 VGPRs). Codes in 4 chunks of 256; d in 8 chunks of 32.
// dot = x_hi*e_hi + x_hi*e_lo + x_lo*e_hi  (3 MFMAs, fp32 accum).
// LDS: 32 KB e-stage UNIONed with 67.6 KB fold buffer (disjoint lifetimes).
// ---------------------------------------------------------------------------
__global__ __launch_bounds__(256, 2) void argmin_mfma(
    const short* __restrict__ xhi, const short* __restrict__ xlo,
    const short* __restrict__ eT, const float* __restrict__ eSq,
    int2* __restrict__ cand) {
  __shared__ __align__(16) char uS[67584];  // union: eS (32 KB) / db (66 KB)
  __shared__ float eSqS[1024];

  short* eS = (short*)uS;
  float2* dbAll = (float2*)uS;

  const int tid = threadIdx.x;
  const int lane = tid & 63;
  const int wid = tid >> 6;
  const int l31 = lane & 31;
  const int lh = lane >> 5;
  const int qBase = blockIdx.x * 128 + wid * 32;

  // stage eSq once (1024 floats)
  *(float4*)(eSqS + tid * 4) = *(const float4*)(eSq + tid * 4);
  __syncthreads();  // eSqS visible to all waves BEFORE first es2 read

  float2* dbW = dbAll + wid * (64 * 33);

  float b1d = 3.4e38f, b2d = 3.4e38f;
  int b1k = 0, b2k = 1;

  const long qRow = (long)(qBase + l31) * DD;

  for (int cc = 0; cc < 4; cc++) {
    f32x16 acc[8];
    #pragma unroll
    for (int ct = 0; ct < 8; ct++)
      #pragma unroll
      for (int i = 0; i < 16; i++) acc[ct][i] = 0.0f;

    float es2[8];
    #pragma unroll
    for (int ct = 0; ct < 8; ct++) es2[ct] = eSqS[cc * 256 + ct * 32 + l31];

    for (int dc = 0; dc < 8; dc++) {
      __syncthreads();  // prior eS/db reads complete
      {
        const char* src = (const char*)(eT + (cc * 8 + dc) * 16384);
        #pragma unroll
        for (int i = 0; i < 8; i++) {
          const int off = i * 4096 + tid * 16;
          *(float4*)(uS + off) = *(const float4*)(src + off);
        }
      }
      __syncthreads();  // tile staged

      #pragma unroll
      for (int ks = 0; ks < 2; ks++) {
        const int d = dc * 32 + ks * 16 + lh * 8;
        const short8 ahi = *(const short8*)(xhi + qRow + d);
        const short8 alo = *(const short8*)(xlo + qRow + d);
        const int db = ks * 2 + lh;
        #pragma unroll
        for (int ct = 0; ct < 8; ct++) {
          const int cL = ct * 32 + l31;
          const short8 bhi = *(const short8*)(eS + ((0 * 4 + db) * 256 + cL) * 8);
          const short8 blo = *(const short8*)(eS + ((1 * 4 + db) * 256 + cL) * 8);
          acc[ct] = __builtin_amdgcn_mfma_f32_32x32x16_bf16(ahi, bhi, acc[ct], 0, 0, 0);
          acc[ct] = __builtin_amdgcn_mfma_f32_32x32x16_bf16(ahi, blo, acc[ct], 0, 0, 0);
          acc[ct] = __builtin_amdgcn_mfma_f32_32x32x16_bf16(alo, bhi, acc[ct], 0, 0, 0);
        }
      }
    }

    __syncthreads();  // all waves done reading eS; uS becomes fold buffer

    // per-(lane,reg): exact best2 over the 8 ct codes; transpose via LDS.
    // db layout per wave: float2 [cand(64)][query(32)+1pad]
    #pragma unroll
    for (int r = 0; r < 16; r++) {
      const int row = (r & 3) + 8 * (r >> 2) + 4 * lh;  // query row 0..31
      float cb1 = 3.4e38f, cb2 = 3.4e38f;
      int ck1 = 0, ck2 = 0;
      #pragma unroll
      for (int ct = 0; ct < 8; ct++) {
        const float dd = es2[ct] - 2.0f * acc[ct][r];
        const int k = cc * 256 + ct * 32 + l31;
        if (dd < cb1) { cb2 = cb1; ck2 = ck1; cb1 = dd; ck1 = k; }
        else if (dd < cb2) { cb2 = dd; ck2 = k; }
      }
      dbW[(l31 * 2 + 0) * 33 + row] = make_float2(cb1, __int_as_float(ck1));
      dbW[(l31 * 2 + 1) * 33 + row] = make_float2(cb2, __int_as_float(ck2));
    }
    __syncthreads();  // transpose visible (also keeps waves phase-aligned)

    // lane (l31, lh) folds candidates lh*32..lh*32+31 for query l31
    #pragma unroll
    for (int i = 0; i < 32; i++) {
      const float2 c = dbW[(lh * 32 + i) * 33 + l31];
      const float dd = c.x;
      const int k = __float_as_int(c.y);
      if (dd < b1d) { b2d = b1d; b2k = b1k; b1d = dd; b1k = k; }
      else if (dd < b2d) { b2d = dd; b2k = k; }
    }
  }

  // merge lane pairs (l, l+32): exact best2 of the union, k-tiebreak
  {
    const float p1d = __shfl_xor(b1d, 32, 64);
    const int p1k = __shfl_xor(b1k, 32, 64);
    const float p2d = __shfl_xor(b2d, 32, 64);
    const int p2k = __shfl_xor(b2k, 32, 64);
    if ((p1d < b1d) || (p1d == b1d && p1k < b1k)) {
      b2d = b1d; b2k = b1k; b1d = p1d; b1k = p1k;
    } else if ((p1d < b2d) || (p1d == b2d && p1k < b2k)) {
      b2d = p1d; b2k = p1k;
    }
    if ((p2d < b1d) || (p2d == b1d && p2k < b1k)) {
      b2d = b1d; b2k = b1k; b1d = p2d; b1k = p2k;
    } else if ((p2d < b2d) || (p2d == b2d && p2k < b2k)) {
      b2d = p2d; b2k = p2k;
    }
  }
  if (lh == 0) cand[qBase + l31] = make_int2(b1k, b2k);
}

// ---------------------------------------------------------------------------
// Kernel 3: exact fp32 rescue of the 2 candidates + gather + codes + SSE
// + code histogram (for the counting sort). One wave per query.
// ---------------------------------------------------------------------------
__global__ __launch_bounds__(256) void gather_rescue(
    const float* __restrict__ x, const float* __restrict__ emb,
    const int2* __restrict__ cand, float* __restrict__ outQ,
    float* __restrict__ outCodes, int* __restrict__ idxFinal,
    float* __restrict__ sseSlots, int* __restrict__ histI) {
  const int lane = threadIdx.x & 63;
  const int n = blockIdx.x * 4 + (threadIdx.x >> 6);
  const int2 kk = cand[n];

  const float4 xv = *(const float4*)(x + n * DD + lane * 4);
  const float4 e1 = *(const float4*)(emb + kk.x * DD + lane * 4);
  const float4 e2 = *(const float4*)(emb + kk.y * DD + lane * 4);

  float p1 = e1.x * (e1.x - 2.0f * xv.x) + e1.y * (e1.y - 2.0f * xv.y) +
             e1.z * (e1.z - 2.0f * xv.z) + e1.w * (e1.w - 2.0f * xv.w);
  float p2 = e2.x * (e2.x - 2.0f * xv.x) + e2.y * (e2.y - 2.0f * xv.y) +
             e2.z * (e2.z - 2.0f * xv.z) + e2.w * (e2.w - 2.0f * xv.w);
  #pragma unroll
  for (int m = 32; m > 0; m >>= 1) {
    p1 += __shfl_xor(p1, m, 64);
    p2 += __shfl_xor(p2, m, 64);
  }
  const bool pick2 = (p2 < p1) || (p2 == p1 && kk.y < kk.x);
  const int ksel = pick2 ? kk.y : kk.x;
  const float4 ev = pick2 ? e2 : e1;

  *(float4*)(outQ + n * DD + lane * 4) = ev;

  const float d0 = ev.x - xv.x, d1 = ev.y - xv.y, d2 = ev.z - xv.z,
              d3 = ev.w - xv.w;
  float s = d0 * d0 + d1 * d1 + d2 * d2 + d3 * d3;
  #pragma unroll
  for (int m = 32; m > 0; m >>= 1) s += __shfl_down(s, m, 64);
  if (lane == 0) {
    atomicAdd(&sseSlots[n & 255], s);
    atomicAdd(&histI[ksel], 1);
    idxFinal[n] = ksel;
    outCodes[n] = (float)ksel;
  }
}

// ---------------------------------------------------------------------------
// Kernel 4: fused prefix-scan + EMA finalize. Single 1024-thread block.
// offs = exclusive prefix sum of histI; also new_cluster_size, norm, losses.
// ---------------------------------------------------------------------------
__global__ __launch_bounds__(1024) void scanfin(
    const float* __restrict__ ema_cs, const int* __restrict__ histI,
    const float* __restrict__ sseSlots, int* __restrict__ offs,
    float* __restrict__ norm, float* __restrict__ outCS,
    float* __restrict__ outLoss) {
  __shared__ int s[1024];
  __shared__ float red[1024];
  const int t = threadIdx.x;
  const int v = histI[t];
  s[t] = v;
  const float ncs = DECAY_F * ema_cs[t] + OMD_F * (float)v;
  outCS[t] = ncs;
  red[t] = ncs;
  __syncthreads();
  // Hillis-Steele inclusive scan -> exclusive via subtracting v
  for (int off = 1; off < 1024; off <<= 1) {
    const int add = (t >= off) ? s[t - off] : 0;
    __syncthreads();
    s[t] += add;
    __syncthreads();
  }
  offs[t] = s[t] - v;
  // n = sum(new_cluster_size)
  for (int st = 512; st > 0; st >>= 1) {
    if (t < st) red[t] += red[t + st];
    __syncthreads();
  }
  const float n = red[0];
  __syncthreads();
  norm[t] = (ncs + EPS_F) / (n + (float)KN * EPS_F) * n;
  // SSE total
  red[t] = (t < 256) ? sseSlots[t] : 0.0f;
  __syncthreads();
  for (int st = 512; st > 0; st >>= 1) {
    if (t < st) red[t] += red[t + st];
    __syncthreads();
  }
  if (t == 0) {
    const float mse = red[0] * (1.0f / 16777216.0f);
    outLoss[0] = 0.25f * mse;  // commitment
    outLoss[1] = mse;          // codebook
  }
}

// ---------------------------------------------------------------------------
// Kernel 5: counting-sort scatter: perm[offs[k] + cursor[k]++] = n.
// ---------------------------------------------------------------------------
__global__ __launch_bounds__(256) void scatter_kernel(
    const int* __restrict__ idxF, const int* __restrict__ offs,
    int* __restrict__ cursor, int* __restrict__ perm) {
  const int n = blockIdx.x * 256 + threadIdx.x;
  const int k = idxF[n];
  const int p = atomicAdd(&cursor[k], 1);
  perm[offs[k] + p] = n;
}

// ---------------------------------------------------------------------------
// Kernel 6: dw[k] = sum of x rows in this code's perm segment.
// One block per code; thread d owns dimension d; no barriers, no big LDS.
// ---------------------------------------------------------------------------
__global__ __launch_bounds__(256) void dw_sum(
    const float* __restrict__ x, const int* __restrict__ perm,
    const int* __restrict__ offs, const int* __restrict__ histI,
    float* __restrict__ dw) {
  const int k = blockIdx.x;
  const int d = threadIdx.x;
  const int beg = offs[k];
  const int c = histI[k];
  float acc = 0.0f;
  int i = 0;
  for (; i + 7 < c; i += 8) {
    const float a0 = x[(long)perm[beg + i + 0] * DD + d];
    const float a1 = x[(long)perm[beg + i + 1] * DD + d];
    const float a2 = x[(long)perm[beg + i + 2] * DD + d];
    const float a3 = x[(long)perm[beg + i + 3] * DD + d];
    const float a4 = x[(long)perm[beg + i + 4] * DD + d];
    const float a5 = x[(long)perm[beg + i + 5] * DD + d];
    const float a6 = x[(long)perm[beg + i + 6] * DD + d];
    const float a7 = x[(long)perm[beg + i + 7] * DD + d];
    acc += ((a0 + a1) + (a2 + a3)) + ((a4 + a5) + (a6 + a7));
  }
  for (; i < c; i++) acc += x[(long)perm[beg + i] * DD + d];
  dw[k * DD + d] = acc;
}

// ---------------------------------------------------------------------------
// Kernel 7: new_ema_w and new_embedding.
// ---------------------------------------------------------------------------
__global__ __launch_bounds__(256) void finalize2(
    const float* __restrict__ ema_w, const float* __restrict__ dw,
    const float* __restrict__ norm, float* __restrict__ outEmb,
    float* __restrict__ outW) {
  const int i = blockIdx.x * 256 + threadIdx.x;  // 0..262143
  const float nw = DECAY_F * ema_w[i] + OMD_F * dw[i];
  outW[i] = nw;
  outEmb[i] = nw / norm[i >> 8];
}

// ---------------------------------------------------------------------------
extern "C" void kernel_launch(void* const* d_in, const int* in_sizes, int n_in,
                              void* d_out, int out_size, void* d_ws, size_t ws_size,
                              hipStream_t stream) {
  const float* x = (const float*)d_in[0];        // [65536, 256]
  const float* emb = (const float*)d_in[1];      // [1024, 256]
  const float* ema_cs = (const float*)d_in[2];   // [1024]
  const float* ema_w = (const float*)d_in[3];    // [1024, 256]
  float* out = (float*)d_out;
  float* ws = (float*)d_ws;

  // workspace (float offsets), ~1.34 MB.
  // sseSlots+histI+cursor are contiguous: one 2304-float memset covers them.
  float* eSq = ws + 0;                   // 1024
  float* sseSlots = ws + 1024;           // 256 floats
  int* histI = (int*)(ws + 1280);        // 1024 ints
  int* cursor = (int*)(ws + 2304);       // 1024 ints
  int* offs = (int*)(ws + 3328);         // 1024 ints
  float* dw = ws + 4352;                 // 262144
  float* norm = ws + 266496;             // 1024
  int* idxFinal = (int*)(ws + 267520);   // 65536 ints

  // d_out doubles as scratch (stream-ordered lifetimes)
  short* xhi = (short*)out;                     // out floats [0, 8388608)
  short* xlo = (short*)(out + 8388608);         // out floats [8388608, 16777216)
  short* eT = (short*)(out + 16777216);         // 524288 shorts (dead after argmin)
  int2* cand = (int2*)(out + 17039360);         // 65536 int2 (dead after gather)
  int* perm = (int*)(out + 17039360);           // 65536 ints (dead after dw_sum)

  // final output layout (return-order flat, fp32)
  float* outQ = out;                    // 16777216  quantized_st
  float* outCodes = out + 16777216;     // 65536     codes (as float)
  float* outLoss = out + 16842752;      // 2         commitment, codebook
  float* outEmb = out + 16842754;       // 262144    new_embedding
  float* outCS = out + 17104898;        // 1024      new_cluster_size
  float* outW = out + 17105922;         // 262144    new_ema_w

  (void)hipMemsetAsync(sseSlots, 0, 2304 * sizeof(float), stream);

  split_x<<<NV * DD / (256 * 8), 256, 0, stream>>>(x, xhi, xlo);
  prep_e<<<32, 256, 0, stream>>>(emb, eT);
  esq_kernel<<<KN / 4, 256, 0, stream>>>(emb, eSq);
  argmin_mfma<<<NV / 128, 256, 0, stream>>>(xhi, xlo, eT, eSq, cand);
  gather_rescue<<<NV / 4, 256, 0, stream>>>(x, emb, cand, outQ, outCodes,
                                            idxFinal, sseSlots, histI);
  scanfin<<<1, 1024, 0, stream>>>(ema_cs, histI, sseSlots, offs, norm, outCS,
                                  outLoss);
  scatter_kernel<<<NV / 256, 256, 0, stream>>>(idxFinal, offs, cursor, perm);
  dw_sum<<<KN, 256, 0, stream>>>(x, perm, offs, histI, dw);
  finalize2<<<KN * DD / 256, 256, 0, stream>>>(ema_w, dw, norm, outEmb, outW);
}